// Round 5
// baseline (270.675 us; speedup 1.0000x reference)
//
#include <hip/hip_runtime.h>

#define Hh 128
#define Ww 160
#define Cc 1024
#define HWp (Hh*Ww)

// ---------------------------------------------------------------------------
// DPP cross-lane helpers (VALU latency, no LDS/ds_bpermute).
template<int CTRL>
__device__ __forceinline__ float dppMaxStage(float v) {
    // invalid lanes receive old = -inf (identity for max)
    int t = __builtin_amdgcn_update_dpp((int)0xFF800000, __float_as_int(v),
                                        CTRL, 0xF, 0xF, false);
    return fmaxf(v, __int_as_float(t));
}
// Wave64 max; result returned as a wave-uniform (SGPR) value.
__device__ __forceinline__ float waveMaxDpp(float v) {
    v = dppMaxStage<0x111>(v);   // row_shr:1
    v = dppMaxStage<0x112>(v);   // row_shr:2
    v = dppMaxStage<0x114>(v);   // row_shr:4
    v = dppMaxStage<0x118>(v);   // row_shr:8
    v = dppMaxStage<0x142>(v);   // row_bcast:15
    v = dppMaxStage<0x143>(v);   // row_bcast:31  -> lane63 = wave max
    return __int_as_float(__builtin_amdgcn_readlane(__float_as_int(v), 63));
}
__device__ __forceinline__ float dppRor1(float v) {  // lane l <- lane (l-1)&63
    return __int_as_float(__builtin_amdgcn_update_dpp(0, __float_as_int(v),
                                                      0x13C, 0xF, 0xF, false));
}
__device__ __forceinline__ float dppRol1(float v) {  // lane l <- lane (l+1)&63
    return __int_as_float(__builtin_amdgcn_update_dpp(0, __float_as_int(v),
                                                      0x134, 0xF, 0xF, false));
}

// ---------------------------------------------------------------------------
// Normalize guidance: g (20, H, W) -> kn tables, STRIDE 8 (b128-friendly).
// dir 0,1 (H-scans): kn[(d*HW + t*H + s)*8 + j]   (per-column contiguous)
// dir 2,3 (W-scans): kn[(d*HW + s*W + t)*8 + j]   (per-row contiguous)
__global__ __launch_bounds__(256) void norm_g(const float* __restrict__ g,
                                              float* __restrict__ kn)
{
    int p = blockIdx.x * blockDim.x + threadIdx.x;
    if (p >= HWp) return;
    int s = p / Ww, t = p - s * Ww;
    #pragma unroll
    for (int d = 0; d < 4; ++d) {
        float v[5]; float sum = 0.f;
        #pragma unroll
        for (int j = 0; j < 5; ++j) {
            v[j] = g[(size_t)(5 * d + j) * HWp + p];
            sum += fabsf(v[j]);
        }
        float inv = 1.f / fmaxf(sum, 1e-12f);
        size_t off = (d < 2) ? (((size_t)d * HWp + (size_t)t * Hh + s) * 8)
                             : (((size_t)d * HWp + (size_t)p) * 8);
        #pragma unroll
        for (int j = 0; j < 5; ++j) kn[off + j] = v[j] * inv;
        kn[off + 5] = 0.f; kn[off + 6] = 0.f; kn[off + 7] = 0.f;
    }
}

// ---------------------------------------------------------------------------
// Tiled transposes between (C, HW) and (HW, C).
__global__ __launch_bounds__(256) void transpose_in(const float* __restrict__ in,
                                                    float* __restrict__ out)
{
    __shared__ float tile[32][33];
    int p0 = blockIdx.x * 32, c0 = blockIdx.y * 32;
    int tx = threadIdx.x, ty = threadIdx.y;          // (32, 8)
    #pragma unroll
    for (int i = 0; i < 4; ++i)
        tile[ty + 8 * i][tx] = in[(size_t)(c0 + ty + 8 * i) * HWp + p0 + tx];
    __syncthreads();
    #pragma unroll
    for (int i = 0; i < 4; ++i)
        out[(size_t)(p0 + ty + 8 * i) * Cc + c0 + tx] = tile[tx][ty + 8 * i];
}

__global__ __launch_bounds__(256) void transpose_out(const float* __restrict__ Y,
                                                     float* __restrict__ out)
{
    __shared__ float tile[32][33];
    int c0 = blockIdx.x * 32, p0 = blockIdx.y * 32;
    int tx = threadIdx.x, ty = threadIdx.y;          // (32, 8)
    #pragma unroll
    for (int i = 0; i < 4; ++i)
        tile[ty + 8 * i][tx] = Y[(size_t)(p0 + ty + 8 * i) * Cc + c0 + tx];
    __syncthreads();
    #pragma unroll
    for (int i = 0; i < 4; ++i)
        out[(size_t)(c0 + ty + 8 * i) * HWp + p0 + tx] = tile[tx][ty + 8 * i];
}

// ---------------------------------------------------------------------------
// One directional scan pass, in-place on Y laid out (H, W, C).
// ONE wave per chain; lane l owns channels 256q+4l+e (4 coalesced float4s).
// __launch_bounds__(64, 1): allow up to 512 VGPRs so the depth-4 named
// prefetch ring (64 VGPRs) stays resident instead of being sunk to its uses
// (R2's failure: default occupancy target capped at 64 VGPRs and serialized
// every step on one ~1200cy memory latency).
// All cross-lane traffic is DPP; max semi-dechained (R off critical path,
// pmax chain = 1 FMA/step). Compile-time strides -> provable no-alias between
// this step's stores and the +4-slice prefetch loads.
template<int NSTEPS, long STRIDE, long COLSTRIDE, bool FWD>
__global__ __launch_bounds__(64, 1) void scan_pass(float* __restrict__ Y,
                                                   const float* __restrict__ ktab)
{
    __shared__ float ks_raw[Ww * 8 + 16];
    float* ks = ks_raw + 8;                   // allow kidx = -1 / NSTEPS overread
    const int l = threadIdx.x;

    const float* kt = ktab + (size_t)blockIdx.x * (size_t)(NSTEPS * 8);
    #pragma unroll 4
    for (int i = l; i < NSTEPS * 8; i += 64) ks[i] = kt[i];
    __syncthreads();

    constexpr long SSTEP = FWD ? STRIDE : -STRIDE;
    constexpr int  KSTEP = FWD ? 1 : -1;
    long cur = (long)blockIdx.x * COLSTRIDE + (FWD ? 0L : (long)(NSTEPS - 1) * STRIDE);
    int kidx = FWD ? 0 : NSTEPS - 1;
    const int loff = 4 * l;

    // step 0: out = x (in-place: nothing to store)
    float4 prev[4];
    #pragma unroll
    for (int q = 0; q < 4; ++q)
        prev[q] = *reinterpret_cast<const float4*>(&Y[cur + q * 256 + loff]);
    float mx = -3.4e38f;
    #pragma unroll
    for (int q = 0; q < 4; ++q)
        mx = fmaxf(mx, fmaxf(fmaxf(prev[q].x, prev[q].y),
                             fmaxf(prev[q].z, prev[q].w)));
    float pmax = waveMaxDpp(mx);

    // prefetch x slices 1..4 (NSTEPS >= 128 always)
    float4 xb0[4], xb1[4], xb2[4], xb3[4];
    #pragma unroll
    for (int q = 0; q < 4; ++q)
        xb0[q] = *reinterpret_cast<const float4*>(&Y[cur + 1 * SSTEP + q * 256 + loff]);
    #pragma unroll
    for (int q = 0; q < 4; ++q)
        xb1[q] = *reinterpret_cast<const float4*>(&Y[cur + 2 * SSTEP + q * 256 + loff]);
    #pragma unroll
    for (int q = 0; q < 4; ++q)
        xb2[q] = *reinterpret_cast<const float4*>(&Y[cur + 3 * SSTEP + q * 256 + loff]);
    #pragma unroll
    for (int q = 0; q < 4; ++q)
        xb3[q] = *reinterpret_cast<const float4*>(&Y[cur + 4 * SSTEP + q * 256 + loff]);

    // prefetch k-tuple for step 1 (stride-8 -> b128 + b32)
    kidx += KSTEP;
    float4 pkv = *reinterpret_cast<const float4*>(&ks[kidx * 8]);
    float  pk4 = ks[kidx * 8 + 4];

    cur += SSTEP;   // now at step 1
    int i = 1;

#define STEP(XB)                                                              \
  {                                                                           \
    const float k0 = pkv.x, k1 = pkv.y, k2 = pkv.z, k3 = pkv.w, k4 = pk4;     \
    kidx += KSTEP;                                                            \
    pkv = *reinterpret_cast<const float4*>(&ks[kidx * 8]);                    \
    pk4 = ks[kidx * 8 + 4];                                                   \
    float A[4], B[4];                                                         \
    _Pragma("unroll") for (int q = 0; q < 4; ++q) {                           \
      A[q] = dppRor1(prev[q].w);      /* lane l: prev.w @ (l-1)&63 */         \
      B[q] = dppRol1(prev[q].x);      /* lane l: prev.x @ (l+1)&63 */         \
    }                                                                         \
    float4 pt[4]; float m = -3.4e38f;                                         \
    _Pragma("unroll") for (int q = 0; q < 4; ++q) {                           \
      float pm0 = (l > 0)  ? A[q] : (q > 0 ? A[q - 1] : 0.f);                 \
      float pp3 = (l < 63) ? B[q] : (q < 3 ? B[q + 1] : 0.f);                 \
      float4 p = prev[q], x = XB[q];                                          \
      pt[q].x = k0 * x.x + k1 * p.x + k2 * pm0 + k3 * p.y;                    \
      pt[q].y = k0 * x.y + k1 * p.y + k2 * p.x + k3 * p.z;                    \
      pt[q].z = k0 * x.z + k1 * p.z + k2 * p.y + k3 * p.w;                    \
      pt[q].w = k0 * x.w + k1 * p.w + k2 * p.z + k3 * pp3;                    \
      m = fmaxf(m, fmaxf(fmaxf(pt[q].x, pt[q].y), fmaxf(pt[q].z, pt[q].w)));  \
    }                                                                         \
    if (i + 4 < NSTEPS) {                                                     \
      _Pragma("unroll") for (int q = 0; q < 4; ++q)                           \
        XB[q] = *reinterpret_cast<const float4*>(                             \
            &Y[cur + 4 * SSTEP + q * 256 + loff]);                            \
    }                                                                         \
    float R = waveMaxDpp(m);                                                  \
    _Pragma("unroll") for (int q = 0; q < 4; ++q) {                           \
      prev[q].x = fmaf(k4, pmax, pt[q].x);                                    \
      prev[q].y = fmaf(k4, pmax, pt[q].y);                                    \
      prev[q].z = fmaf(k4, pmax, pt[q].z);                                    \
      prev[q].w = fmaf(k4, pmax, pt[q].w);                                    \
      *reinterpret_cast<float4*>(&Y[cur + q * 256 + loff]) = prev[q];         \
    }                                                                         \
    pmax = fmaf(k4, pmax, R);                                                 \
    cur += SSTEP; ++i;                                                        \
  }

    // 4x-unrolled main loop; slot for step i is xb[(i-1)&3].
    while (i + 3 < NSTEPS) { STEP(xb0) STEP(xb1) STEP(xb2) STEP(xb3) }
    if (i < NSTEPS) STEP(xb0)
    if (i < NSTEPS) STEP(xb1)
    if (i < NSTEPS) STEP(xb2)
#undef STEP
}

// ---------------------------------------------------------------------------
extern "C" void kernel_launch(void* const* d_in, const int* in_sizes, int n_in,
                              void* d_out, int out_size, void* d_ws, size_t ws_size,
                              hipStream_t stream)
{
    const float* x = (const float*)d_in[0];   // (1, 32, 32, 128, 160) = (C,H,W)
    const float* g = (const float*)d_in[1];   // (1, 20, 128, 160)
    float* out = (float*)d_out;

    const size_t kn_bytes = (size_t)4 * HWp * 8 * sizeof(float);   // 2.6 MB
    const size_t y_bytes  = (size_t)Cc * HWp * sizeof(float);      // 84 MB
    if (ws_size < kn_bytes + y_bytes) return;

    float* kn = (float*)d_ws;
    float* Y  = (float*)((char*)d_ws + kn_bytes);

    // 1) normalize guidance into per-chain-contiguous tables (stride 8)
    norm_g<<<(HWp + 255) / 256, 256, 0, stream>>>(g, kn);

    // 2) transpose x (C,HW) -> Y (HW,C)
    transpose_in<<<dim3(HWp / 32, Cc / 32), dim3(32, 8), 0, stream>>>(x, Y);

    // 3) four in-place directional scans on Y (1 wave per chain)
    scan_pass<Hh, (long)Ww * Cc, (long)Cc, true ><<<Ww, 64, 0, stream>>>(
        Y, kn + (size_t)0 * HWp * 8);
    scan_pass<Hh, (long)Ww * Cc, (long)Cc, false><<<Ww, 64, 0, stream>>>(
        Y, kn + (size_t)1 * HWp * 8);
    scan_pass<Ww, (long)Cc, (long)Ww * Cc, true ><<<Hh, 64, 0, stream>>>(
        Y, kn + (size_t)2 * HWp * 8);
    scan_pass<Ww, (long)Cc, (long)Ww * Cc, false><<<Hh, 64, 0, stream>>>(
        Y, kn + (size_t)3 * HWp * 8);

    // 4) transpose Y (HW,C) -> out (C,HW)
    transpose_out<<<dim3(Cc / 32, HWp / 32), dim3(32, 8), 0, stream>>>(Y, out);
}